// Round 10
// baseline (2778.247 us; speedup 1.0000x reference)
//
#include <hip/hip_runtime.h>
#include <hip/hip_bf16.h>

#define TT    128
#define BATCH 1024
#define INDIM 512
#define HIDD  1024
#define NCLS  10

typedef __bf16 bf16x8 __attribute__((ext_vector_type(8)));
typedef float  f32x4  __attribute__((ext_vector_type(4)));
typedef unsigned short u16x8 __attribute__((ext_vector_type(8)));

__device__ __forceinline__ unsigned short bf16b(float f) {
    __hip_bfloat16 h = __float2bfloat16(f);
    return __builtin_bit_cast(unsigned short, h);
}

__device__ __forceinline__ float tanh_fast(float x) {
    float e = __expf(2.0f * x);
    return 1.0f - 2.0f * __builtin_amdgcn_rcpf(e + 1.0f);
}

#define WAITV(n) asm volatile("s_waitcnt vmcnt(" #n ")" ::: "memory")
#define WAITL()  asm volatile("s_waitcnt lgkmcnt(0)" ::: "memory")
#define BAR()    asm volatile("s_barrier" ::: "memory")

// ---------------------------------------------------------------------------
// Prep: W -> transposed bf16 hi/lo pairs (unchanged, verified R1-R9).
// ---------------------------------------------------------------------------
__global__ __launch_bounds__(256) void prep_kernel(
    const float* __restrict__ Whh, const float* __restrict__ Wxh,
    __hip_bfloat16* __restrict__ WhhT_hi, __hip_bfloat16* __restrict__ WhhT_lo,
    __hip_bfloat16* __restrict__ WxhT_hi, __hip_bfloat16* __restrict__ WxhT_lo)
{
    __shared__ float tl[64][68];
    int bid = blockIdx.x, tid = threadIdx.x;
    const float* src; int N, k0, n0, dstride;
    __hip_bfloat16 *dhi, *dlo;
    if (bid < 256) { src = Whh; N = 1024; k0 = (bid >> 4) << 6; n0 = (bid & 15) << 6;
                     dhi = WhhT_hi; dlo = WhhT_lo; dstride = 1024; }
    else { int b = bid - 256; src = Wxh; N = 1024; k0 = (b >> 4) << 6; n0 = (b & 15) << 6;
           dhi = WxhT_hi; dlo = WxhT_lo; dstride = 512; }

    int r = tid >> 2, c0 = (tid & 3) << 4;
    const float* s = src + (size_t)(k0 + r) * N + n0 + c0;
#pragma unroll
    for (int j = 0; j < 4; ++j)
        *(float4*)&tl[r][c0 + j * 4] = *(const float4*)(s + j * 4);
    __syncthreads();

    int rn = tid >> 2, ck0 = (tid & 3) << 4;
    u16x8 hi0, hi1, lo0, lo1;
#pragma unroll
    for (int j = 0; j < 16; ++j) {
        float w = tl[ck0 + j][rn];
        unsigned short hb = bf16b(w);
        float hf = __bfloat162float(__builtin_bit_cast(__hip_bfloat16, hb));
        unsigned short lb = bf16b(w - hf);
        if (j < 8) { hi0[j] = hb; lo0[j] = lb; }
        else       { hi1[j - 8] = hb; lo1[j - 8] = lb; }
    }
    size_t o = (size_t)(n0 + rn) * dstride + k0 + ck0;
    *(u16x8*)(void*)(dhi + o)     = hi0;
    *(u16x8*)(void*)(dhi + o + 8) = hi1;
    *(u16x8*)(void*)(dlo + o)     = lo0;
    *(u16x8*)(void*)(dlo + o + 8) = lo1;
}

// ---------------------------------------------------------------------------
__global__ __launch_bounds__(256) void convx_all_kernel(
    const float* __restrict__ x, __hip_bfloat16* __restrict__ xs)
{
    size_t gid = (size_t)blockIdx.x * 256 + threadIdx.x;
    int i  = (int)(gid & 63) << 3;
    size_t bt = gid >> 6;
    int t = (int)(bt & 127);
    int b = (int)(bt >> 7);
    const float* s = x + ((size_t)b * TT + t) * INDIM + i;
    float4 a0 = *(const float4*)s, a1 = *(const float4*)(s + 4);
    u16x8 o;
    o[0]=bf16b(a0.x); o[1]=bf16b(a0.y); o[2]=bf16b(a0.z); o[3]=bf16b(a0.w);
    o[4]=bf16b(a1.x); o[5]=bf16b(a1.y); o[6]=bf16b(a1.z); o[7]=bf16b(a1.w);
    *(u16x8*)(void*)(xs + ((size_t)t * BATCH + b) * INDIM + i) = o;
}

__global__ __launch_bounds__(256) void zero_kernel(
    __hip_bfloat16* __restrict__ h, unsigned* __restrict__ bar)
{
    if (blockIdx.x < 512) {
        size_t i = ((size_t)blockIdx.x * 256 + threadIdx.x) << 3;
        u16x8 z = {0,0,0,0,0,0,0,0};
        *(u16x8*)(void*)(h + i) = z;
    } else {
        uint4 z = {0,0,0,0};
#pragma unroll
        for (int k = 0; k < 8; ++k)
            ((uint4*)bar)[k * 256 + threadIdx.x] = z;
    }
}

// ---------------------------------------------------------------------------
// Persistent RNN, R10: 2x2 wave split. Wave w: kh=w&1 (K-half), nh=w>>1
// (col-half, 32 cols). B frags/wave = 96 (384 regs), acc = 8 f32x4 (32 regs).
// Each chunk read by 2 waves (not 4): per-CU LDS reads halve vs R7.
// Buffers (9 x 16KB): x(t) fixed @ b0-b3; h round A: h0,h1,h2->b4,b5,b8 /
// h4,h5->b6,b7; round B: h3->b5, h6->b6, h7->b7. Partials (cross-K reduce)
// reuse b8. Every stage->read edge: per-wave WAITV + BAR (6 BAR/step).
// MFMA order: hi-pass 8 indep, then lo-pass (dependent distance 8).
// ---------------------------------------------------------------------------
#define BUF(i) (smem + ((i) << 14))

#define FRAGA(_b, m, ks) \
    (*(const bf16x8*)((_b) + ((((m)<<4)+ar) << 8) + ((((((ks)<<2)+kg)) ^ (ar & 7)) << 4)))

#define STAGE(basePtr, rs, bufidx, AUX) do {                                   \
    _Pragma("unroll")                                                          \
    for (int _i = 0; _i < 4; ++_i) {                                           \
        int _r = (_i << 4) + (tid >> 4);                                       \
        int _s = (tid & 15) ^ (_r & 7);                                        \
        const void* _g = (const void*)((basePtr) + (size_t)_r * (rs) + (_s << 3)); \
        void* _l = (void*)(smem + ((bufidx) << 14) + (_i << 12) + (wave << 10));   \
        __builtin_amdgcn_global_load_lds(                                      \
            (const __attribute__((address_space(1))) void*)_g,                 \
            (__attribute__((address_space(3))) void*)_l, 16, 0, AUX);          \
    } } while (0)

// One 64rows x 128K chunk for this wave: 16 A-reads, 64 MFMAs into acc[4][2].
#define MF(a_, b_, c_) c_ = __builtin_amdgcn_mfma_f32_16x16x32_bf16(a_, b_, c_, 0,0,0)
#define DO_CHUNK(B_ARR, q, bufptr) do {                                        \
    const char* _b = (const char*)(bufptr);                                    \
    _Pragma("unroll")                                                          \
    for (int _ks = 0; _ks < 4; ++_ks) {                                        \
        bf16x8 a0 = FRAGA(_b, 0, _ks), a1 = FRAGA(_b, 1, _ks);                 \
        bf16x8 a2 = FRAGA(_b, 2, _ks), a3 = FRAGA(_b, 3, _ks);                 \
        bf16x8 b00 = B_ARR[(q)*16 + _ks*4 + 0], b01 = B_ARR[(q)*16 + _ks*4 + 2]; \
        bf16x8 b10 = B_ARR[(q)*16 + _ks*4 + 1], b11 = B_ARR[(q)*16 + _ks*4 + 3]; \
        MF(a0, b00, acc[0][0]); MF(a1, b00, acc[1][0]);                        \
        MF(a2, b00, acc[2][0]); MF(a3, b00, acc[3][0]);                        \
        MF(a0, b01, acc[0][1]); MF(a1, b01, acc[1][1]);                        \
        MF(a2, b01, acc[2][1]); MF(a3, b01, acc[3][1]);                        \
        MF(a0, b10, acc[0][0]); MF(a1, b10, acc[1][0]);                        \
        MF(a2, b10, acc[2][0]); MF(a3, b10, acc[3][0]);                        \
        MF(a0, b11, acc[0][1]); MF(a1, b11, acc[1][1]);                        \
        MF(a2, b11, acc[2][1]); MF(a3, b11, acc[3][1]);                        \
    } } while (0)

__global__ __launch_bounds__(256, 1) void rnn_kernel(
    __hip_bfloat16* __restrict__ h0, __hip_bfloat16* __restrict__ h1,
    const __hip_bfloat16* __restrict__ xs,
    const __hip_bfloat16* __restrict__ WhhT_hi, const __hip_bfloat16* __restrict__ WhhT_lo,
    const __hip_bfloat16* __restrict__ WxhT_hi, const __hip_bfloat16* __restrict__ WxhT_lo,
    const float* __restrict__ b_xh, const float* __restrict__ b_hh,
    unsigned* __restrict__ bar)
{
    __shared__ char smem[147456];                // 9 x 16KB
    int tid = threadIdx.x, bid = blockIdx.x;
    int by = (bid & 7) | (((bid >> 3) & 1) << 3);   // XCD-local groups (R6)
    int bx = bid >> 4;
    int lane = tid & 63, wave = tid >> 6;
    int kh = wave & 1, nh = wave >> 1;
    int ar = lane & 15, kg = lane >> 4;
    int bx64 = bx << 6, by64 = by << 6;

    // ---- weights: Bh[q*16+ks*4+cg*2+hl] for h-chunks kh*4+q (q=0..3);
    //      Bx[q*16+ks*4+cg*2+hl] for x-chunks kh*2+q (q=0..1). 384 regs. ----
    bf16x8 Bh[64], Bx[32];
    float bias[2];
#pragma unroll
    for (int cg = 0; cg < 2; ++cg) {
        int col = bx64 + (nh << 5) + (cg << 4) + ar;
        bias[cg] = b_xh[col] + b_hh[col];
#pragma unroll
        for (int q = 0; q < 4; ++q)
#pragma unroll
            for (int ks = 0; ks < 4; ++ks) {
                int k = (((kh << 2) + q) << 7) + (ks << 5) + (kg << 3);
                Bh[q*16 + ks*4 + cg*2 + 0] = *(const bf16x8*)(WhhT_hi + (size_t)col * HIDD + k);
                Bh[q*16 + ks*4 + cg*2 + 1] = *(const bf16x8*)(WhhT_lo + (size_t)col * HIDD + k);
            }
#pragma unroll
        for (int q = 0; q < 2; ++q)
#pragma unroll
            for (int ks = 0; ks < 4; ++ks) {
                int k = (((kh << 1) + q) << 7) + (ks << 5) + (kg << 3);
                Bx[q*16 + ks*4 + cg*2 + 0] = *(const bf16x8*)(WxhT_hi + (size_t)col * INDIM + k);
                Bx[q*16 + ks*4 + cg*2 + 1] = *(const bf16x8*)(WxhT_lo + (size_t)col * INDIM + k);
            }
    }

    unsigned* grpflags = bar + (by << 9);
    unsigned* myflag   = grpflags + (bx << 5);

    // Prologue: x(0) -> b0..b3.
    {
        const __hip_bfloat16* xA0 = xs + (size_t)by64 * INDIM;
        STAGE(xA0 + 0*128, INDIM, 0, 0);
        STAGE(xA0 + 1*128, INDIM, 1, 0);
        STAGE(xA0 + 2*128, INDIM, 2, 0);
        STAGE(xA0 + 3*128, INDIM, 3, 0);
    }
    WAITV(0); BAR();

    for (int t = 0; t < TT; ++t) {
        const __hip_bfloat16* hA = (t & 1) ? h1 : h0;
        __hip_bfloat16*       hB = (t & 1) ? h0 : h1;
        const __hip_bfloat16* hR = hA + (size_t)by64 * HIDD;
        const __hip_bfloat16* xN = xs + (size_t)(t + 1) * (BATCH * INDIM)
                                      + (size_t)by64 * INDIM;
        int nl = (t < TT - 1);

        f32x4 acc[4][2];
#pragma unroll
        for (int m = 0; m < 4; ++m) { acc[m][0] = (f32x4){0,0,0,0}; acc[m][1] = (f32x4){0,0,0,0}; }

        // ===== x phase: kh0 reads b0,b1; kh1 reads b2,b3 (resident) ========
        if (kh == 0) { DO_CHUNK(Bx, 0, BUF(0)); DO_CHUNK(Bx, 1, BUF(1)); }
        else         { DO_CHUNK(Bx, 0, BUF(2)); DO_CHUNK(Bx, 1, BUF(3)); }

        // ===== poll peers (wave0, vm queue quiet), then BAR1 ===============
        if (t > 0 && wave == 0) {
            unsigned tgt = (unsigned)t;
            for (;;) {
                unsigned v = tgt;
                if (lane < 16)
                    v = __hip_atomic_load(grpflags + (lane << 5), __ATOMIC_RELAXED,
                                          __HIP_MEMORY_SCOPE_AGENT);
                if (__all(v >= tgt)) break;
                __builtin_amdgcn_s_sleep(1);
            }
        }
        BAR();

        // ===== stage A: 5 h-chunks + x'(4) =================================
        STAGE(hR + 0*128, HIDD, 4, 1);           // h0  (ops  1-4)
        STAGE(hR + 1*128, HIDD, 5, 1);           // h1  (5-8)
        STAGE(hR + 2*128, HIDD, 8, 1);           // h2  (9-12)
        STAGE(hR + 4*128, HIDD, 6, 1);           // h4  (13-16)
        STAGE(hR + 5*128, HIDD, 7, 1);           // h5  (17-20)
        if (nl) {
            STAGE(xN + 0*128, INDIM, 0, 0);      // x'  (21-36)
            STAGE(xN + 1*128, INDIM, 1, 0);
            STAGE(xN + 2*128, INDIM, 2, 0);
            STAGE(xN + 3*128, INDIM, 3, 0);
            WAITV(16);                           // h0..h5 in (x' in flight)
        } else {
            WAITV(0);
        }
        BAR();                                   // BAR2a: chunks visible to all

        if (kh == 0) { DO_CHUNK(Bh, 0, BUF(4)); DO_CHUNK(Bh, 1, BUF(5)); DO_CHUNK(Bh, 2, BUF(8)); }
        else         { DO_CHUNK(Bh, 0, BUF(6)); DO_CHUNK(Bh, 1, BUF(7)); }
        BAR();                                   // BAR2b: round-A reads done

        // ===== stage B: h3->b5, h6->b6, h7->b7 =============================
        STAGE(hR + 3*128, HIDD, 5, 1);
        STAGE(hR + 6*128, HIDD, 6, 1);
        STAGE(hR + 7*128, HIDD, 7, 1);
        WAITV(0);
        BAR();                                   // BAR3a: B chunks visible

        if (kh == 0) { DO_CHUNK(Bh, 3, BUF(5)); }
        else         { DO_CHUNK(Bh, 2, BUF(6)); DO_CHUNK(Bh, 3, BUF(7)); }

        // ===== cross-K reduction: exchange 2 row-tiles via b8 ==============
        {
            char* pw = smem + (8 << 14) + (wave << 12);
            int mo = kh ? 0 : 2;                 // outgoing row-tiles
#pragma unroll
            for (int s = 0; s < 2; ++s)
#pragma unroll
                for (int cg = 0; cg < 2; ++cg)
                    *(f32x4*)(pw + (((s << 1) | cg) << 10) + (lane << 4)) = acc[mo + s][cg];
        }
        WAITL(); BAR();                          // BAR4: partials visible

        {
            const char* pr = smem + (8 << 14) + ((wave ^ 1) << 12);
            int mk = kh ? 2 : 0;                 // kept row-tiles
#pragma unroll
            for (int s = 0; s < 2; ++s)
#pragma unroll
                for (int cg = 0; cg < 2; ++cg)
                    acc[mk + s][cg] += *(const f32x4*)(pr + (((s << 1) | cg) << 10) + (lane << 4));

            // epilogue: bias + tanh + store my 32 rows x 32 cols
#pragma unroll
            for (int s = 0; s < 2; ++s)
#pragma unroll
                for (int cg = 0; cg < 2; ++cg) {
                    int col = bx64 + (nh << 5) + (cg << 4) + ar;
                    f32x4 a = acc[mk + s][cg];
#pragma unroll
                    for (int j = 0; j < 4; ++j) {
                        int row = by64 + ((mk + s) << 4) + (kg << 2) + j;
                        hB[(size_t)row * HIDD + col] = __float2bfloat16(tanh_fast(a[j] + bias[cg]));
                    }
                }
        }
        WAITV(0);                                // h stores drained
        BAR();                                   // BAR5
        if (nl && tid == 0)
            __hip_atomic_store(myflag, (unsigned)(t + 1), __ATOMIC_RELAXED,
                               __HIP_MEMORY_SCOPE_AGENT);
    }
}

// ---------------------------------------------------------------------------
__global__ __launch_bounds__(64) void out_kernel(
    const __hip_bfloat16* __restrict__ h, const float* __restrict__ Why,
    const float* __restrict__ b_y, float* __restrict__ out)
{
    int b = blockIdx.x, lane = threadIdx.x;
    float acc[NCLS];
#pragma unroll
    for (int c = 0; c < NCLS; ++c) acc[c] = 0.f;
    for (int kk = 0; kk < 16; ++kk) {
        int k = (kk << 6) + lane;
        float hv = __bfloat162float(h[(size_t)b * HIDD + k]);
#pragma unroll
        for (int c = 0; c < NCLS; ++c) acc[c] += hv * Why[(size_t)k * NCLS + c];
    }
#pragma unroll
    for (int c = 0; c < NCLS; ++c) {
        float v = acc[c];
#pragma unroll
        for (int off = 32; off > 0; off >>= 1) v += __shfl_down(v, off);
        if (lane == 0) out[(size_t)b * NCLS + c] = v + b_y[c];
    }
}

// ---------------------------------------------------------------------------
extern "C" void kernel_launch(void* const* d_in, const int* in_sizes, int n_in,
                              void* d_out, int out_size, void* d_ws, size_t ws_size,
                              hipStream_t stream)
{
    const float* x    = (const float*)d_in[0];
    const float* Wxh  = (const float*)d_in[1];
    const float* b_xh = (const float*)d_in[2];
    const float* Whh  = (const float*)d_in[3];
    const float* b_hh = (const float*)d_in[4];
    const float* Why  = (const float*)d_in[5];
    const float* b_y  = (const float*)d_in[6];
    float* out = (float*)d_out;

    char* ws = (char*)d_ws;                       // 144 MB used
    __hip_bfloat16* WhhT_hi = (__hip_bfloat16*)(ws);
    __hip_bfloat16* WhhT_lo = (__hip_bfloat16*)(ws + (2u  << 20));
    __hip_bfloat16* WxhT_hi = (__hip_bfloat16*)(ws + (4u  << 20));
    __hip_bfloat16* WxhT_lo = (__hip_bfloat16*)(ws + (5u  << 20));
    __hip_bfloat16* h0      = (__hip_bfloat16*)(ws + (6u  << 20));
    __hip_bfloat16* h1      = (__hip_bfloat16*)(ws + (8u  << 20));
    unsigned*       bar     = (unsigned*)      (ws + (10u << 20));
    __hip_bfloat16* xs      = (__hip_bfloat16*)(ws + (16u << 20));  // 128 MB

    prep_kernel<<<384, 256, 0, stream>>>(Whh, Wxh, WhhT_hi, WhhT_lo, WxhT_hi, WxhT_lo);
    convx_all_kernel<<<32768, 256, 0, stream>>>(x, xs);
    zero_kernel<<<513, 256, 0, stream>>>(h0, bar);

    rnn_kernel<<<256, 256, 0, stream>>>(h0, h1, xs,
                                        WhhT_hi, WhhT_lo, WxhT_hi, WxhT_lo,
                                        b_xh, b_hh, bar);

    out_kernel<<<1024, 64, 0, stream>>>(h0, Why, b_y, out);  // final h is in h0
}

// Round 12
// 880.575 us; speedup vs baseline: 3.1550x; 3.1550x over previous
//
#include <hip/hip_runtime.h>
#include <hip/hip_bf16.h>

#define TT    128
#define BATCH 1024
#define INDIM 512
#define HIDD  1024
#define NCLS  10

typedef __bf16 bf16x8 __attribute__((ext_vector_type(8)));
typedef float  f32x4  __attribute__((ext_vector_type(4)));
typedef unsigned short u16x8 __attribute__((ext_vector_type(8)));

__device__ __forceinline__ unsigned short bf16b(float f) {
    __hip_bfloat16 h = __float2bfloat16(f);
    return __builtin_bit_cast(unsigned short, h);
}

__device__ __forceinline__ float tanh_fast(float x) {
    float e = __expf(2.0f * x);
    return 1.0f - 2.0f * __builtin_amdgcn_rcpf(e + 1.0f);
}

#define WAITV(n) asm volatile("s_waitcnt vmcnt(" #n ")" ::: "memory")
#define WAITL()  asm volatile("s_waitcnt lgkmcnt(0)" ::: "memory")
#define BAR()    asm volatile("s_barrier" ::: "memory")

// ---------------------------------------------------------------------------
// Prep: W -> transposed bf16 hi/lo pairs (unchanged, verified R1-R11).
// (Wxh lo is still produced; the step kernel simply no longer loads it.)
// ---------------------------------------------------------------------------
__global__ __launch_bounds__(256) void prep_kernel(
    const float* __restrict__ Whh, const float* __restrict__ Wxh,
    __hip_bfloat16* __restrict__ WhhT_hi, __hip_bfloat16* __restrict__ WhhT_lo,
    __hip_bfloat16* __restrict__ WxhT_hi, __hip_bfloat16* __restrict__ WxhT_lo)
{
    __shared__ float tl[64][68];
    int bid = blockIdx.x, tid = threadIdx.x;
    const float* src; int N, k0, n0, dstride;
    __hip_bfloat16 *dhi, *dlo;
    if (bid < 256) { src = Whh; N = 1024; k0 = (bid >> 4) << 6; n0 = (bid & 15) << 6;
                     dhi = WhhT_hi; dlo = WhhT_lo; dstride = 1024; }
    else { int b = bid - 256; src = Wxh; N = 1024; k0 = (b >> 4) << 6; n0 = (b & 15) << 6;
           dhi = WxhT_hi; dlo = WxhT_lo; dstride = 512; }

    int r = tid >> 2, c0 = (tid & 3) << 4;
    const float* s = src + (size_t)(k0 + r) * N + n0 + c0;
#pragma unroll
    for (int j = 0; j < 4; ++j)
        *(float4*)&tl[r][c0 + j * 4] = *(const float4*)(s + j * 4);
    __syncthreads();

    int rn = tid >> 2, ck0 = (tid & 3) << 4;
    u16x8 hi0, hi1, lo0, lo1;
#pragma unroll
    for (int j = 0; j < 16; ++j) {
        float w = tl[ck0 + j][rn];
        unsigned short hb = bf16b(w);
        float hf = __bfloat162float(__builtin_bit_cast(__hip_bfloat16, hb));
        unsigned short lb = bf16b(w - hf);
        if (j < 8) { hi0[j] = hb; lo0[j] = lb; }
        else       { hi1[j - 8] = hb; lo1[j - 8] = lb; }
    }
    size_t o = (size_t)(n0 + rn) * dstride + k0 + ck0;
    *(u16x8*)(void*)(dhi + o)     = hi0;
    *(u16x8*)(void*)(dhi + o + 8) = hi1;
    *(u16x8*)(void*)(dlo + o)     = lo0;
    *(u16x8*)(void*)(dlo + o + 8) = lo1;
}

// ---------------------------------------------------------------------------
__global__ __launch_bounds__(256) void convx_all_kernel(
    const float* __restrict__ x, __hip_bfloat16* __restrict__ xs)
{
    size_t gid = (size_t)blockIdx.x * 256 + threadIdx.x;
    int i  = (int)(gid & 63) << 3;
    size_t bt = gid >> 6;
    int t = (int)(bt & 127);
    int b = (int)(bt >> 7);
    const float* s = x + ((size_t)b * TT + t) * INDIM + i;
    float4 a0 = *(const float4*)s, a1 = *(const float4*)(s + 4);
    u16x8 o;
    o[0]=bf16b(a0.x); o[1]=bf16b(a0.y); o[2]=bf16b(a0.z); o[3]=bf16b(a0.w);
    o[4]=bf16b(a1.x); o[5]=bf16b(a1.y); o[6]=bf16b(a1.z); o[7]=bf16b(a1.w);
    *(u16x8*)(void*)(xs + ((size_t)t * BATCH + b) * INDIM + i) = o;
}

__global__ __launch_bounds__(256) void zero_kernel(
    __hip_bfloat16* __restrict__ h, unsigned* __restrict__ bar)
{
    if (blockIdx.x < 512) {
        size_t i = ((size_t)blockIdx.x * 256 + threadIdx.x) << 3;
        u16x8 z = {0,0,0,0,0,0,0,0};
        *(u16x8*)(void*)(h + i) = z;
    } else {
        uint4 z = {0,0,0,0};
#pragma unroll
        for (int k = 0; k < 8; ++k)
            ((uint4*)bar)[k * 256 + threadIdx.x] = z;
    }
}

// ---------------------------------------------------------------------------
// Persistent RNN, R12: 2x2 wave split (kh=w&1 K-half, nh=w>>1 col-half),
// REDUCED register pressure: Whh hi+lo (Bh 64 frags, AGPR) but Wxh HI ONLY
// (Bx 16 frags) -> ~420 live regs, ~90 slack (R11's 508-edge codegen hazard
// mitigated). Waits follow R10's PROVEN discipline: all 4 x' staged early in
// round A (WAITV(16) keeps them in flight), round B stages then WAITV(0).
// All acc indices static. 9x16KB bufs: x @ b0-b3, h @ b4-b7, reduce @ b8.
// ---------------------------------------------------------------------------
#define BUF(i) (smem + ((i) << 14))

#define FRAGA(_b, m, ks) \
    (*(const bf16x8*)((_b) + ((((m)<<4)+ar) << 8) + ((((((ks)<<2)+kg)) ^ (ar & 7)) << 4)))

#define STAGE(basePtr, rs, bufidx, AUX) do {                                   \
    _Pragma("unroll")                                                          \
    for (int _i = 0; _i < 4; ++_i) {                                           \
        int _r = (_i << 4) + (tid >> 4);                                       \
        int _s = (tid & 15) ^ (_r & 7);                                        \
        const void* _g = (const void*)((basePtr) + (size_t)_r * (rs) + (_s << 3)); \
        void* _l = (void*)(smem + ((bufidx) << 14) + (_i << 12) + (wave << 10));   \
        __builtin_amdgcn_global_load_lds(                                      \
            (const __attribute__((address_space(1))) void*)_g,                 \
            (__attribute__((address_space(3))) void*)_l, 16, 0, AUX);          \
    } } while (0)

#define MF(a_, b_, c_) c_ = __builtin_amdgcn_mfma_f32_16x16x32_bf16(a_, b_, c_, 0,0,0)

// h chunk: hi+lo, 64 MFMAs.
#define DO_CHUNK_H(q, bufptr) do {                                             \
    const char* _b = (const char*)(bufptr);                                    \
    _Pragma("unroll")                                                          \
    for (int _ks = 0; _ks < 4; ++_ks) {                                        \
        bf16x8 a0 = FRAGA(_b, 0, _ks), a1 = FRAGA(_b, 1, _ks);                 \
        bf16x8 a2 = FRAGA(_b, 2, _ks), a3 = FRAGA(_b, 3, _ks);                 \
        bf16x8 b00 = Bh[(q)*16 + _ks*4 + 0], b01 = Bh[(q)*16 + _ks*4 + 2];     \
        bf16x8 b10 = Bh[(q)*16 + _ks*4 + 1], b11 = Bh[(q)*16 + _ks*4 + 3];     \
        MF(a0, b00, acc00); MF(a1, b00, acc10);                                \
        MF(a2, b00, acc20); MF(a3, b00, acc30);                                \
        MF(a0, b01, acc01); MF(a1, b01, acc11);                                \
        MF(a2, b01, acc21); MF(a3, b01, acc31);                                \
        MF(a0, b10, acc00); MF(a1, b10, acc10);                                \
        MF(a2, b10, acc20); MF(a3, b10, acc30);                                \
        MF(a0, b11, acc01); MF(a1, b11, acc11);                                \
        MF(a2, b11, acc21); MF(a3, b11, acc31);                                \
    } } while (0)

// x chunk: hi only, 32 MFMAs.
#define DO_CHUNK_X(q, bufptr) do {                                             \
    const char* _b = (const char*)(bufptr);                                    \
    _Pragma("unroll")                                                          \
    for (int _ks = 0; _ks < 4; ++_ks) {                                        \
        bf16x8 a0 = FRAGA(_b, 0, _ks), a1 = FRAGA(_b, 1, _ks);                 \
        bf16x8 a2 = FRAGA(_b, 2, _ks), a3 = FRAGA(_b, 3, _ks);                 \
        bf16x8 bx0 = Bx[(q)*8 + _ks*2 + 0], bx1 = Bx[(q)*8 + _ks*2 + 1];       \
        MF(a0, bx0, acc00); MF(a1, bx0, acc10);                                \
        MF(a2, bx0, acc20); MF(a3, bx0, acc30);                                \
        MF(a0, bx1, acc01); MF(a1, bx1, acc11);                                \
        MF(a2, bx1, acc21); MF(a3, bx1, acc31);                                \
    } } while (0)

__global__ __launch_bounds__(256, 1) void rnn_kernel(
    __hip_bfloat16* __restrict__ h0, __hip_bfloat16* __restrict__ h1,
    const __hip_bfloat16* __restrict__ xs,
    const __hip_bfloat16* __restrict__ WhhT_hi, const __hip_bfloat16* __restrict__ WhhT_lo,
    const __hip_bfloat16* __restrict__ WxhT_hi, const __hip_bfloat16* __restrict__ WxhT_lo,
    const float* __restrict__ b_xh, const float* __restrict__ b_hh,
    unsigned* __restrict__ bar)
{
    __shared__ char smem[147456];                // 9 x 16KB
    int tid = threadIdx.x, bid = blockIdx.x;
    int by = (bid & 7) | (((bid >> 3) & 1) << 3);   // XCD-local groups (R6)
    int bx = bid >> 4;
    int lane = tid & 63, wave = tid >> 6;
    int kh = wave & 1, nh = wave >> 1;
    int ar = lane & 15, kg = lane >> 4;
    int bx64 = bx << 6, by64 = by << 6;

    // ---- weights: Bh (hi+lo, 64 frags) for h-chunks kh*4+q; Bx (hi only,
    //      16 frags) for x-chunks kh*2+q. ~320 weight regs total. ----
    bf16x8 Bh[64], Bx[16];
    float bias0, bias1;
    {
        int col0 = bx64 + (nh << 5) + ar;
        bias0 = b_xh[col0] + b_hh[col0];
        bias1 = b_xh[col0 + 16] + b_hh[col0 + 16];
#pragma unroll
        for (int cg = 0; cg < 2; ++cg) {
            int col = bx64 + (nh << 5) + (cg << 4) + ar;
#pragma unroll
            for (int q = 0; q < 4; ++q)
#pragma unroll
                for (int ks = 0; ks < 4; ++ks) {
                    int k = (((kh << 2) + q) << 7) + (ks << 5) + (kg << 3);
                    Bh[q*16 + ks*4 + cg*2 + 0] = *(const bf16x8*)(WhhT_hi + (size_t)col * HIDD + k);
                    Bh[q*16 + ks*4 + cg*2 + 1] = *(const bf16x8*)(WhhT_lo + (size_t)col * HIDD + k);
                }
#pragma unroll
            for (int q = 0; q < 2; ++q)
#pragma unroll
                for (int ks = 0; ks < 4; ++ks) {
                    int k = (((kh << 1) + q) << 7) + (ks << 5) + (kg << 3);
                    Bx[q*8 + ks*2 + cg] = *(const bf16x8*)(WxhT_hi + (size_t)col * INDIM + k);
                }
        }
    }

    unsigned* grpflags = bar + (by << 9);
    unsigned* myflag   = grpflags + (bx << 5);

    // Prologue: x(0) -> b0..b3.
    {
        const __hip_bfloat16* xA0 = xs + (size_t)by64 * INDIM;
        STAGE(xA0 + 0*128, INDIM, 0, 0);
        STAGE(xA0 + 1*128, INDIM, 1, 0);
        STAGE(xA0 + 2*128, INDIM, 2, 0);
        STAGE(xA0 + 3*128, INDIM, 3, 0);
    }
    WAITV(0); BAR();

    for (int t = 0; t < TT; ++t) {
        const __hip_bfloat16* hA = (t & 1) ? h1 : h0;
        __hip_bfloat16*       hB = (t & 1) ? h0 : h1;
        const __hip_bfloat16* hR = hA + (size_t)by64 * HIDD;
        const __hip_bfloat16* xN = xs + (size_t)(t + 1) * (BATCH * INDIM)
                                      + (size_t)by64 * INDIM;
        int nl = (t < TT - 1);

        f32x4 acc00 = {0,0,0,0}, acc01 = {0,0,0,0};
        f32x4 acc10 = {0,0,0,0}, acc11 = {0,0,0,0};
        f32x4 acc20 = {0,0,0,0}, acc21 = {0,0,0,0};
        f32x4 acc30 = {0,0,0,0}, acc31 = {0,0,0,0};

        // ===== x phase: kh0 reads b0,b1; kh1 reads b2,b3 ===================
        if (kh == 0) { DO_CHUNK_X(0, BUF(0)); DO_CHUNK_X(1, BUF(1)); }
        else         { DO_CHUNK_X(0, BUF(2)); DO_CHUNK_X(1, BUF(3)); }

        // ===== poll peers (wave0, vm queue quiet), then BAR1 ===============
        if (t > 0 && wave == 0) {
            unsigned tgt = (unsigned)t;
            for (;;) {
                unsigned v = tgt;
                if (lane < 16)
                    v = __hip_atomic_load(grpflags + (lane << 5), __ATOMIC_RELAXED,
                                          __HIP_MEMORY_SCOPE_AGENT);
                if (__all(v >= tgt)) break;
                __builtin_amdgcn_s_sleep(1);
            }
        }
        BAR();                                   // BAR1: x bufs free, h(t) ready

        // ===== round A: stage h0,h1,h4,h5 + ALL x' (R10's pattern) =========
        STAGE(hR + 0*128, HIDD, 4, 1);           // ops  1-4
        STAGE(hR + 1*128, HIDD, 5, 1);           // ops  5-8
        STAGE(hR + 4*128, HIDD, 6, 1);           // ops  9-12
        STAGE(hR + 5*128, HIDD, 7, 1);           // ops 13-16
        if (nl) {
            STAGE(xN + 0*128, INDIM, 0, 0);      // ops 17-32 (long flight)
            STAGE(xN + 1*128, INDIM, 1, 0);
            STAGE(xN + 2*128, INDIM, 2, 0);
            STAGE(xN + 3*128, INDIM, 3, 0);
            WAITV(16);                           // h in; x' flying
        } else {
            WAITV(0);
        }
        BAR();                                   // BAR2: round A visible

        if (kh == 0) { DO_CHUNK_H(0, BUF(4)); DO_CHUNK_H(1, BUF(5)); }
        else         { DO_CHUNK_H(0, BUF(6)); DO_CHUNK_H(1, BUF(7)); }
        BAR();                                   // BAR3: round A reads done

        // ===== round B: stage h2,h3,h6,h7; full drain (R10's pattern) ======
        STAGE(hR + 2*128, HIDD, 4, 1);
        STAGE(hR + 3*128, HIDD, 5, 1);
        STAGE(hR + 6*128, HIDD, 6, 1);
        STAGE(hR + 7*128, HIDD, 7, 1);
        WAITV(0);                                // h round B + x' all in
        BAR();                                   // BAR3b: round B visible

        if (kh == 0) { DO_CHUNK_H(2, BUF(4)); DO_CHUNK_H(3, BUF(5)); }
        else         { DO_CHUNK_H(2, BUF(6)); DO_CHUNK_H(3, BUF(7)); }

        // ===== cross-K reduction via b8 (all indices static) ===============
        {
            char* pw = smem + (8 << 14) + (wave << 12);
            if (kh == 0) {                       // send rows 32-63
                *(f32x4*)(pw +    0 + (lane << 4)) = acc20;
                *(f32x4*)(pw + 1024 + (lane << 4)) = acc21;
                *(f32x4*)(pw + 2048 + (lane << 4)) = acc30;
                *(f32x4*)(pw + 3072 + (lane << 4)) = acc31;
            } else {                             // send rows 0-31
                *(f32x4*)(pw +    0 + (lane << 4)) = acc00;
                *(f32x4*)(pw + 1024 + (lane << 4)) = acc01;
                *(f32x4*)(pw + 2048 + (lane << 4)) = acc10;
                *(f32x4*)(pw + 3072 + (lane << 4)) = acc11;
            }
        }
        WAITL(); BAR();                          // BAR4: partials visible

        {
            const char* pr = smem + (8 << 14) + ((wave ^ 1) << 12);
            f32x4 p0 = *(const f32x4*)(pr +    0 + (lane << 4));
            f32x4 p1 = *(const f32x4*)(pr + 1024 + (lane << 4));
            f32x4 p2 = *(const f32x4*)(pr + 2048 + (lane << 4));
            f32x4 p3 = *(const f32x4*)(pr + 3072 + (lane << 4));
            int colb = bx64 + (nh << 5) + ar;
            if (kh == 0) {                       // keep rows 0-31
                acc00 += p0; acc01 += p1; acc10 += p2; acc11 += p3;
#pragma unroll
                for (int j = 0; j < 4; ++j) {
                    int r0 = by64 + (kg << 2) + j;
                    hB[(size_t)r0 * HIDD + colb]             = __float2bfloat16(tanh_fast(acc00[j] + bias0));
                    hB[(size_t)r0 * HIDD + colb + 16]        = __float2bfloat16(tanh_fast(acc01[j] + bias1));
                    hB[(size_t)(r0 + 16) * HIDD + colb]      = __float2bfloat16(tanh_fast(acc10[j] + bias0));
                    hB[(size_t)(r0 + 16) * HIDD + colb + 16] = __float2bfloat16(tanh_fast(acc11[j] + bias1));
                }
            } else {                             // keep rows 32-63
                acc20 += p0; acc21 += p1; acc30 += p2; acc31 += p3;
#pragma unroll
                for (int j = 0; j < 4; ++j) {
                    int r0 = by64 + 32 + (kg << 2) + j;
                    hB[(size_t)r0 * HIDD + colb]             = __float2bfloat16(tanh_fast(acc20[j] + bias0));
                    hB[(size_t)r0 * HIDD + colb + 16]        = __float2bfloat16(tanh_fast(acc21[j] + bias1));
                    hB[(size_t)(r0 + 16) * HIDD + colb]      = __float2bfloat16(tanh_fast(acc30[j] + bias0));
                    hB[(size_t)(r0 + 16) * HIDD + colb + 16] = __float2bfloat16(tanh_fast(acc31[j] + bias1));
                }
            }
        }
        WAITV(0);                                // h stores drained
        BAR();                                   // BAR5
        if (nl && tid == 0)
            __hip_atomic_store(myflag, (unsigned)(t + 1), __ATOMIC_RELAXED,
                               __HIP_MEMORY_SCOPE_AGENT);
    }
}

// ---------------------------------------------------------------------------
__global__ __launch_bounds__(64) void out_kernel(
    const __hip_bfloat16* __restrict__ h, const float* __restrict__ Why,
    const float* __restrict__ b_y, float* __restrict__ out)
{
    int b = blockIdx.x, lane = threadIdx.x;
    float acc[NCLS];
#pragma unroll
    for (int c = 0; c < NCLS; ++c) acc[c] = 0.f;
    for (int kk = 0; kk < 16; ++kk) {
        int k = (kk << 6) + lane;
        float hv = __bfloat162float(h[(size_t)b * HIDD + k]);
#pragma unroll
        for (int c = 0; c < NCLS; ++c) acc[c] += hv * Why[(size_t)k * NCLS + c];
    }
#pragma unroll
    for (int c = 0; c < NCLS; ++c) {
        float v = acc[c];
#pragma unroll
        for (int off = 32; off > 0; off >>= 1) v += __shfl_down(v, off);
        if (lane == 0) out[(size_t)b * NCLS + c] = v + b_y[c];
    }
}

// ---------------------------------------------------------------------------
extern "C" void kernel_launch(void* const* d_in, const int* in_sizes, int n_in,
                              void* d_out, int out_size, void* d_ws, size_t ws_size,
                              hipStream_t stream)
{
    const float* x    = (const float*)d_in[0];
    const float* Wxh  = (const float*)d_in[1];
    const float* b_xh = (const float*)d_in[2];
    const float* Whh  = (const float*)d_in[3];
    const float* b_hh = (const float*)d_in[4];
    const float* Why  = (const float*)d_in[5];
    const float* b_y  = (const float*)d_in[6];
    float* out = (float*)d_out;

    char* ws = (char*)d_ws;                       // 144 MB used
    __hip_bfloat16* WhhT_hi = (__hip_bfloat16*)(ws);
    __hip_bfloat16* WhhT_lo = (__hip_bfloat16*)(ws + (2u  << 20));
    __hip_bfloat16* WxhT_hi = (__hip_bfloat16*)(ws + (4u  << 20));
    __hip_bfloat16* WxhT_lo = (__hip_bfloat16*)(ws + (5u  << 20));
    __hip_bfloat16* h0      = (__hip_bfloat16*)(ws + (6u  << 20));
    __hip_bfloat16* h1      = (__hip_bfloat16*)(ws + (8u  << 20));
    unsigned*       bar     = (unsigned*)      (ws + (10u << 20));
    __hip_bfloat16* xs      = (__hip_bfloat16*)(ws + (16u << 20));  // 128 MB

    prep_kernel<<<384, 256, 0, stream>>>(Whh, Wxh, WhhT_hi, WhhT_lo, WxhT_hi, WxhT_lo);
    convx_all_kernel<<<32768, 256, 0, stream>>>(x, xs);
    zero_kernel<<<513, 256, 0, stream>>>(h0, bar);

    rnn_kernel<<<256, 256, 0, stream>>>(h0, h1, xs,
                                        WhhT_hi, WhhT_lo, WxhT_hi, WxhT_lo,
                                        b_xh, b_hh, bar);

    out_kernel<<<1024, 64, 0, stream>>>(h0, Why, b_y, out);  // final h is in h0
}

// Round 13
// 854.357 us; speedup vs baseline: 3.2519x; 1.0307x over previous
//
#include <hip/hip_runtime.h>
#include <hip/hip_bf16.h>

#define TT    128
#define BATCH 1024
#define INDIM 512
#define HIDD  1024
#define NCLS  10

typedef __bf16 bf16x8 __attribute__((ext_vector_type(8)));
typedef float  f32x4  __attribute__((ext_vector_type(4)));
typedef unsigned short u16x8 __attribute__((ext_vector_type(8)));

__device__ __forceinline__ unsigned short bf16b(float f) {
    __hip_bfloat16 h = __float2bfloat16(f);
    return __builtin_bit_cast(unsigned short, h);
}

__device__ __forceinline__ float tanh_fast(float x) {
    float e = __expf(2.0f * x);
    return 1.0f - 2.0f * __builtin_amdgcn_rcpf(e + 1.0f);
}

#define WAITV(n) asm volatile("s_waitcnt vmcnt(" #n ")" ::: "memory")
#define WAITL()  asm volatile("s_waitcnt lgkmcnt(0)" ::: "memory")
#define BAR()    asm volatile("s_barrier" ::: "memory")

// ---------------------------------------------------------------------------
// Prep: W -> transposed bf16 hi/lo pairs (unchanged, verified R1-R12).
// ---------------------------------------------------------------------------
__global__ __launch_bounds__(256) void prep_kernel(
    const float* __restrict__ Whh, const float* __restrict__ Wxh,
    __hip_bfloat16* __restrict__ WhhT_hi, __hip_bfloat16* __restrict__ WhhT_lo,
    __hip_bfloat16* __restrict__ WxhT_hi, __hip_bfloat16* __restrict__ WxhT_lo)
{
    __shared__ float tl[64][68];
    int bid = blockIdx.x, tid = threadIdx.x;
    const float* src; int N, k0, n0, dstride;
    __hip_bfloat16 *dhi, *dlo;
    if (bid < 256) { src = Whh; N = 1024; k0 = (bid >> 4) << 6; n0 = (bid & 15) << 6;
                     dhi = WhhT_hi; dlo = WhhT_lo; dstride = 1024; }
    else { int b = bid - 256; src = Wxh; N = 1024; k0 = (b >> 4) << 6; n0 = (b & 15) << 6;
           dhi = WxhT_hi; dlo = WxhT_lo; dstride = 512; }

    int r = tid >> 2, c0 = (tid & 3) << 4;
    const float* s = src + (size_t)(k0 + r) * N + n0 + c0;
#pragma unroll
    for (int j = 0; j < 4; ++j)
        *(float4*)&tl[r][c0 + j * 4] = *(const float4*)(s + j * 4);
    __syncthreads();

    int rn = tid >> 2, ck0 = (tid & 3) << 4;
    u16x8 hi0, hi1, lo0, lo1;
#pragma unroll
    for (int j = 0; j < 16; ++j) {
        float w = tl[ck0 + j][rn];
        unsigned short hb = bf16b(w);
        float hf = __bfloat162float(__builtin_bit_cast(__hip_bfloat16, hb));
        unsigned short lb = bf16b(w - hf);
        if (j < 8) { hi0[j] = hb; lo0[j] = lb; }
        else       { hi1[j - 8] = hb; lo1[j - 8] = lb; }
    }
    size_t o = (size_t)(n0 + rn) * dstride + k0 + ck0;
    *(u16x8*)(void*)(dhi + o)     = hi0;
    *(u16x8*)(void*)(dhi + o + 8) = hi1;
    *(u16x8*)(void*)(dlo + o)     = lo0;
    *(u16x8*)(void*)(dlo + o + 8) = lo1;
}

// ---------------------------------------------------------------------------
__global__ __launch_bounds__(256) void convx_all_kernel(
    const float* __restrict__ x, __hip_bfloat16* __restrict__ xs)
{
    size_t gid = (size_t)blockIdx.x * 256 + threadIdx.x;
    int i  = (int)(gid & 63) << 3;
    size_t bt = gid >> 6;
    int t = (int)(bt & 127);
    int b = (int)(bt >> 7);
    const float* s = x + ((size_t)b * TT + t) * INDIM + i;
    float4 a0 = *(const float4*)s, a1 = *(const float4*)(s + 4);
    u16x8 o;
    o[0]=bf16b(a0.x); o[1]=bf16b(a0.y); o[2]=bf16b(a0.z); o[3]=bf16b(a0.w);
    o[4]=bf16b(a1.x); o[5]=bf16b(a1.y); o[6]=bf16b(a1.z); o[7]=bf16b(a1.w);
    *(u16x8*)(void*)(xs + ((size_t)t * BATCH + b) * INDIM + i) = o;
}

__global__ __launch_bounds__(256) void zero_kernel(
    __hip_bfloat16* __restrict__ h, unsigned* __restrict__ bar)
{
    if (blockIdx.x < 512) {
        size_t i = ((size_t)blockIdx.x * 256 + threadIdx.x) << 3;
        u16x8 z = {0,0,0,0,0,0,0,0};
        *(u16x8*)(void*)(h + i) = z;
    } else {
        uint4 z = {0,0,0,0};
#pragma unroll
        for (int k = 0; k < 8; ++k)
            ((uint4*)bar)[k * 256 + threadIdx.x] = z;
    }
}

// ---------------------------------------------------------------------------
// Persistent RNN, R13: 8 waves (512 thr) = 2 waves/SIMD for TLP. Wave w:
// kh=w>>1 (K-quarter: h-K [kh*256,+256), x-K [kh*128,+128)), nh=w&1 (32 cols).
// Regs/wave ~230 (Bh 32 frags + Bx 8 + acc 8 f32x4) -> fits 2/SIMD.
// Bufs: x @ b0-3 (chunk kh <-> buf kh); h rounds A/B @ b4-7 (kh <-> b4+kh,
// round A = even h-chunks 2kh, round B = odd 2kh+1). Reduction: 4-way along
// K via 64x1KB tile grid spanning b4-b7 (free post-compute), static indices.
// Schedule = R12's proven 7-BAR shape, counted vmcnt.
// ---------------------------------------------------------------------------
#define BUF(i) (smem + ((i) << 14))

#define FRAGA(_b, m, ks) \
    (*(const bf16x8*)((_b) + ((((m)<<4)+ar) << 8) + ((((((ks)<<2)+kg)) ^ (ar & 7)) << 4)))

// 512-thread cooperative stage of one 64row x 128K chunk (16KB): 2 ops/thread.
#define STAGE(basePtr, rs, bufidx, AUX) do {                                   \
    _Pragma("unroll")                                                          \
    for (int _i = 0; _i < 2; ++_i) {                                           \
        int _r = (_i << 5) + (tid >> 4);                                       \
        int _s = (tid & 15) ^ (_r & 7);                                        \
        const void* _g = (const void*)((basePtr) + (size_t)_r * (rs) + (_s << 3)); \
        void* _l = (void*)(smem + ((bufidx) << 14) + (_i << 13) + (wave << 10));   \
        __builtin_amdgcn_global_load_lds(                                      \
            (const __attribute__((address_space(1))) void*)_g,                 \
            (__attribute__((address_space(3))) void*)_l, 16, 0, AUX);          \
    } } while (0)

#define MF(a_, b_, c_) c_ = __builtin_amdgcn_mfma_f32_16x16x32_bf16(a_, b_, c_, 0,0,0)

// h chunk q (0/1 within this kh): hi+lo, 64 MFMAs; dep distance 8.
#define DO_CHUNK_H(q, bufptr) do {                                             \
    const char* _b = (const char*)(bufptr);                                    \
    _Pragma("unroll")                                                          \
    for (int _ks = 0; _ks < 4; ++_ks) {                                        \
        bf16x8 a0 = FRAGA(_b, 0, _ks), a1 = FRAGA(_b, 1, _ks);                 \
        bf16x8 a2 = FRAGA(_b, 2, _ks), a3 = FRAGA(_b, 3, _ks);                 \
        bf16x8 h00 = Bh[(q)*16 + _ks*4 + 0], h01 = Bh[(q)*16 + _ks*4 + 2];     \
        bf16x8 h10 = Bh[(q)*16 + _ks*4 + 1], h11 = Bh[(q)*16 + _ks*4 + 3];     \
        MF(a0, h00, acc00); MF(a1, h00, acc10);                                \
        MF(a2, h00, acc20); MF(a3, h00, acc30);                                \
        MF(a0, h01, acc01); MF(a1, h01, acc11);                                \
        MF(a2, h01, acc21); MF(a3, h01, acc31);                                \
        MF(a0, h10, acc00); MF(a1, h10, acc10);                                \
        MF(a2, h10, acc20); MF(a3, h10, acc30);                                \
        MF(a0, h11, acc01); MF(a1, h11, acc11);                                \
        MF(a2, h11, acc21); MF(a3, h11, acc31);                                \
    } } while (0)

// x chunk (one per kh): hi only, 32 MFMAs.
#define DO_CHUNK_X(bufptr) do {                                                \
    const char* _b = (const char*)(bufptr);                                    \
    _Pragma("unroll")                                                          \
    for (int _ks = 0; _ks < 4; ++_ks) {                                        \
        bf16x8 a0 = FRAGA(_b, 0, _ks), a1 = FRAGA(_b, 1, _ks);                 \
        bf16x8 a2 = FRAGA(_b, 2, _ks), a3 = FRAGA(_b, 3, _ks);                 \
        bf16x8 x0 = Bx[_ks*2 + 0], x1 = Bx[_ks*2 + 1];                         \
        MF(a0, x0, acc00); MF(a1, x0, acc10);                                  \
        MF(a2, x0, acc20); MF(a3, x0, acc30);                                  \
        MF(a0, x1, acc01); MF(a1, x1, acc11);                                  \
        MF(a2, x1, acc21); MF(a3, x1, acc31);                                  \
    } } while (0)

// Reduction tile (cg, m, writer-kh j): 1KB per tile, grid spans b4..b7.
#define REDT(cg_, m_, j_) \
    (smem + (4 << 14) + (((((nh << 1) | (cg_)) << 4) | (((m_) << 2) | (j_))) << 10) + (lane << 4))

__global__ __launch_bounds__(512, 2) void rnn_kernel(
    __hip_bfloat16* __restrict__ h0, __hip_bfloat16* __restrict__ h1,
    const __hip_bfloat16* __restrict__ xs,
    const __hip_bfloat16* __restrict__ WhhT_hi, const __hip_bfloat16* __restrict__ WhhT_lo,
    const __hip_bfloat16* __restrict__ WxhT_hi, const __hip_bfloat16* __restrict__ WxhT_lo,
    const float* __restrict__ b_xh, const float* __restrict__ b_hh,
    unsigned* __restrict__ bar)
{
    __shared__ char smem[147456];                // 9 x 16KB
    int tid = threadIdx.x, bid = blockIdx.x;
    int by = (bid & 7) | (((bid >> 3) & 1) << 3);   // XCD-local groups (R6)
    int bx = bid >> 4;
    int lane = tid & 63, wave = tid >> 6;
    int kh = wave >> 1, nh = wave & 1;
    int ar = lane & 15, kg = lane >> 4;
    int bx64 = bx << 6, by64 = by << 6;

    // ---- weights: Bh 32 frags (h chunks 2kh,2kh+1), Bx 8 frags (x chunk kh).
    bf16x8 Bh[32], Bx[8];
    float bias0, bias1;
    {
        int col0 = bx64 + (nh << 5) + ar;
        bias0 = b_xh[col0] + b_hh[col0];
        bias1 = b_xh[col0 + 16] + b_hh[col0 + 16];
#pragma unroll
        for (int cg = 0; cg < 2; ++cg) {
            int col = bx64 + (nh << 5) + (cg << 4) + ar;
#pragma unroll
            for (int q = 0; q < 2; ++q)
#pragma unroll
                for (int ks = 0; ks < 4; ++ks) {
                    int k = (((kh << 1) + q) << 7) + (ks << 5) + (kg << 3);
                    Bh[q*16 + ks*4 + cg*2 + 0] = *(const bf16x8*)(WhhT_hi + (size_t)col * HIDD + k);
                    Bh[q*16 + ks*4 + cg*2 + 1] = *(const bf16x8*)(WhhT_lo + (size_t)col * HIDD + k);
                }
#pragma unroll
            for (int ks = 0; ks < 4; ++ks) {
                int k = (kh << 7) + (ks << 5) + (kg << 3);
                Bx[ks*2 + cg] = *(const bf16x8*)(WxhT_hi + (size_t)col * INDIM + k);
            }
        }
    }

    unsigned* grpflags = bar + (by << 9);
    unsigned* myflag   = grpflags + (bx << 5);

    // Prologue: x(0) chunks 0-3 -> b0-3.
    {
        const __hip_bfloat16* xA0 = xs + (size_t)by64 * INDIM;
        STAGE(xA0 + 0*128, INDIM, 0, 0);
        STAGE(xA0 + 1*128, INDIM, 1, 0);
        STAGE(xA0 + 2*128, INDIM, 2, 0);
        STAGE(xA0 + 3*128, INDIM, 3, 0);
    }
    WAITV(0); BAR();

    for (int t = 0; t < TT; ++t) {
        const __hip_bfloat16* hA = (t & 1) ? h1 : h0;
        __hip_bfloat16*       hB = (t & 1) ? h0 : h1;
        const __hip_bfloat16* hR = hA + (size_t)by64 * HIDD;
        const __hip_bfloat16* xN = xs + (size_t)(t + 1) * (BATCH * INDIM)
                                      + (size_t)by64 * INDIM;
        int nl = (t < TT - 1);

        f32x4 acc00 = {0,0,0,0}, acc01 = {0,0,0,0};
        f32x4 acc10 = {0,0,0,0}, acc11 = {0,0,0,0};
        f32x4 acc20 = {0,0,0,0}, acc21 = {0,0,0,0};
        f32x4 acc30 = {0,0,0,0}, acc31 = {0,0,0,0};

        // ===== x phase: wave reads its own x chunk (buf kh, resident) ======
        DO_CHUNK_X(BUF(kh));

        // ===== poll peers (wave0 only), then BAR1 ==========================
        if (t > 0 && wave == 0) {
            unsigned tgt = (unsigned)t;
            for (;;) {
                unsigned v = tgt;
                if (lane < 16)
                    v = __hip_atomic_load(grpflags + (lane << 5), __ATOMIC_RELAXED,
                                          __HIP_MEMORY_SCOPE_AGENT);
                if (__all(v >= tgt)) break;
                __builtin_amdgcn_s_sleep(1);
            }
        }
        BAR();                                   // BAR1: x bufs free, h(t) ready

        // ===== round A: stage even h-chunks {0,2,4,6} + all x' =============
        STAGE(hR + 0*128, HIDD, 4, 1);           // ops 1-2
        STAGE(hR + 2*128, HIDD, 5, 1);           // 3-4
        STAGE(hR + 4*128, HIDD, 6, 1);           // 5-6
        STAGE(hR + 6*128, HIDD, 7, 1);           // 7-8
        if (nl) {
            STAGE(xN + 0*128, INDIM, 0, 0);      // 9-16 (long flight)
            STAGE(xN + 1*128, INDIM, 1, 0);
            STAGE(xN + 2*128, INDIM, 2, 0);
            STAGE(xN + 3*128, INDIM, 3, 0);
            WAITV(8);                            // h landed; x' flying
        } else {
            WAITV(0);
        }
        BAR();                                   // BAR2: round A visible

        DO_CHUNK_H(0, BUF(4 + kh));              // chunk 2kh
        BAR();                                   // BAR3: round A reads done

        // ===== round B: stage odd h-chunks {1,3,5,7} =======================
        STAGE(hR + 1*128, HIDD, 4, 1);
        STAGE(hR + 3*128, HIDD, 5, 1);
        STAGE(hR + 5*128, HIDD, 6, 1);
        STAGE(hR + 7*128, HIDD, 7, 1);
        WAITV(0);                                // round B + x' all in
        BAR();                                   // BAR3b: round B visible

        DO_CHUNK_H(1, BUF(4 + kh));              // chunk 2kh+1
        BAR();                                   // BAR4: b4-7 reads done

        // ===== 4-way cross-K reduction (static branches on kh) =============
        if (kh == 0) {
            *(f32x4*)REDT(0,1,0) = acc10; *(f32x4*)REDT(1,1,0) = acc11;
            *(f32x4*)REDT(0,2,0) = acc20; *(f32x4*)REDT(1,2,0) = acc21;
            *(f32x4*)REDT(0,3,0) = acc30; *(f32x4*)REDT(1,3,0) = acc31;
        } else if (kh == 1) {
            *(f32x4*)REDT(0,0,1) = acc00; *(f32x4*)REDT(1,0,1) = acc01;
            *(f32x4*)REDT(0,2,1) = acc20; *(f32x4*)REDT(1,2,1) = acc21;
            *(f32x4*)REDT(0,3,1) = acc30; *(f32x4*)REDT(1,3,1) = acc31;
        } else if (kh == 2) {
            *(f32x4*)REDT(0,0,2) = acc00; *(f32x4*)REDT(1,0,2) = acc01;
            *(f32x4*)REDT(0,1,2) = acc10; *(f32x4*)REDT(1,1,2) = acc11;
            *(f32x4*)REDT(0,3,2) = acc30; *(f32x4*)REDT(1,3,2) = acc31;
        } else {
            *(f32x4*)REDT(0,0,3) = acc00; *(f32x4*)REDT(1,0,3) = acc01;
            *(f32x4*)REDT(0,1,3) = acc10; *(f32x4*)REDT(1,1,3) = acc11;
            *(f32x4*)REDT(0,2,3) = acc20; *(f32x4*)REDT(1,2,3) = acc21;
        }
        WAITL(); BAR();                          // BAR4b: partials visible

        {
            f32x4 s0, s1;
            if (kh == 0) {
                s0 = acc00 + *(const f32x4*)REDT(0,0,1) + *(const f32x4*)REDT(0,0,2) + *(const f32x4*)REDT(0,0,3);
                s1 = acc01 + *(const f32x4*)REDT(1,0,1) + *(const f32x4*)REDT(1,0,2) + *(const f32x4*)REDT(1,0,3);
            } else if (kh == 1) {
                s0 = acc10 + *(const f32x4*)REDT(0,1,0) + *(const f32x4*)REDT(0,1,2) + *(const f32x4*)REDT(0,1,3);
                s1 = acc11 + *(const f32x4*)REDT(1,1,0) + *(const f32x4*)REDT(1,1,2) + *(const f32x4*)REDT(1,1,3);
            } else if (kh == 2) {
                s0 = acc20 + *(const f32x4*)REDT(0,2,0) + *(const f32x4*)REDT(0,2,1) + *(const f32x4*)REDT(0,2,3);
                s1 = acc21 + *(const f32x4*)REDT(1,2,0) + *(const f32x4*)REDT(1,2,1) + *(const f32x4*)REDT(1,2,3);
            } else {
                s0 = acc30 + *(const f32x4*)REDT(0,3,0) + *(const f32x4*)REDT(0,3,1) + *(const f32x4*)REDT(0,3,2);
                s1 = acc31 + *(const f32x4*)REDT(1,3,0) + *(const f32x4*)REDT(1,3,1) + *(const f32x4*)REDT(1,3,2);
            }
            // epilogue: wave stores rows [by64+kh*16, +16) x its 32 cols.
            int colb = bx64 + (nh << 5) + ar;
#pragma unroll
            for (int j = 0; j < 4; ++j) {
                int row = by64 + (kh << 4) + (kg << 2) + j;
                hB[(size_t)row * HIDD + colb]      = __float2bfloat16(tanh_fast(s0[j] + bias0));
                hB[(size_t)row * HIDD + colb + 16] = __float2bfloat16(tanh_fast(s1[j] + bias1));
            }
        }
        WAITV(0);                                // h stores drained
        BAR();                                   // BAR5
        if (nl && tid == 0)
            __hip_atomic_store(myflag, (unsigned)(t + 1), __ATOMIC_RELAXED,
                               __HIP_MEMORY_SCOPE_AGENT);
    }
}

// ---------------------------------------------------------------------------
__global__ __launch_bounds__(64) void out_kernel(
    const __hip_bfloat16* __restrict__ h, const float* __restrict__ Why,
    const float* __restrict__ b_y, float* __restrict__ out)
{
    int b = blockIdx.x, lane = threadIdx.x;
    float acc[NCLS];
#pragma unroll
    for (int c = 0; c < NCLS; ++c) acc[c] = 0.f;
    for (int kk = 0; kk < 16; ++kk) {
        int k = (kk << 6) + lane;
        float hv = __bfloat162float(h[(size_t)b * HIDD + k]);
#pragma unroll
        for (int c = 0; c < NCLS; ++c) acc[c] += hv * Why[(size_t)k * NCLS + c];
    }
#pragma unroll
    for (int c = 0; c < NCLS; ++c) {
        float v = acc[c];
#pragma unroll
        for (int off = 32; off > 0; off >>= 1) v += __shfl_down(v, off);
        if (lane == 0) out[(size_t)b * NCLS + c] = v + b_y[c];
    }
}

// ---------------------------------------------------------------------------
extern "C" void kernel_launch(void* const* d_in, const int* in_sizes, int n_in,
                              void* d_out, int out_size, void* d_ws, size_t ws_size,
                              hipStream_t stream)
{
    const float* x    = (const float*)d_in[0];
    const float* Wxh  = (const float*)d_in[1];
    const float* b_xh = (const float*)d_in[2];
    const float* Whh  = (const float*)d_in[3];
    const float* b_hh = (const float*)d_in[4];
    const float* Why  = (const float*)d_in[5];
    const float* b_y  = (const float*)d_in[6];
    float* out = (float*)d_out;

    char* ws = (char*)d_ws;                       // 144 MB used
    __hip_bfloat16* WhhT_hi = (__hip_bfloat16*)(ws);
    __hip_bfloat16* WhhT_lo = (__hip_bfloat16*)(ws + (2u  << 20));
    __hip_bfloat16* WxhT_hi = (__hip_bfloat16*)(ws + (4u  << 20));
    __hip_bfloat16* WxhT_lo = (__hip_bfloat16*)(ws + (5u  << 20));
    __hip_bfloat16* h0      = (__hip_bfloat16*)(ws + (6u  << 20));
    __hip_bfloat16* h1      = (__hip_bfloat16*)(ws + (8u  << 20));
    unsigned*       bar     = (unsigned*)      (ws + (10u << 20));
    __hip_bfloat16* xs      = (__hip_bfloat16*)(ws + (16u << 20));  // 128 MB

    prep_kernel<<<384, 256, 0, stream>>>(Whh, Wxh, WhhT_hi, WhhT_lo, WxhT_hi, WxhT_lo);
    convx_all_kernel<<<32768, 256, 0, stream>>>(x, xs);
    zero_kernel<<<513, 256, 0, stream>>>(h0, bar);

    rnn_kernel<<<256, 512, 0, stream>>>(h0, h1, xs,
                                        WhhT_hi, WhhT_lo, WxhT_hi, WxhT_lo,
                                        b_xh, b_hh, bar);

    out_kernel<<<1024, 64, 0, stream>>>(h0, Why, b_y, out);  // final h is in h0
}